// Round 3
// baseline (506.521 us; speedup 1.0000x reference)
//
#include <hip/hip_runtime.h>

// StarLoss: mean over (B,N) of
//   (1/sqrt(lam1)+eps)*d1 + (1/sqrt(lam2)+eps)*d2 + 0.5*omega*(lam1+lam2)
// d1,d2 are GLOBAL sums -> 5 scalar sums S1..S5; final = (S1*S3+S2*S4+.5*S5)/M.
//
// R7: probe the LDS-DMA return path. R5/R6 established the VGPR-return read
// path saturates at ~4.1 TB/s regardless of mapping (R5: +23%) or software
// pipelining (R6: null). Little's law: demand-side in-flight (~32 waves x 6
// loads x 0.7KB) >> observed BW x latency (~8KB/CU) -> the cap is a
// service-side in-flight-line limit (~48-64 line-fill slots/CU) on vector
// returns. global_load_lds returns to LDS, not VGPRs; if its tracking is
// separate/deeper, the cap breaks. Wave-private double-buffer (NO barriers),
// 2 DMA calls per 64-elem iter:
//   call 1: full wave, 16B/lane  -> cov   (1KB)
//   call 2: lanes 0-31 source pred pairs, lanes 32-63 source tgt pairs (1KB)
// Explicit counted s_waitcnt vmcnt(2) ping-pong keeps the next buffer's 2
// calls in flight while consuming the current one. LDS 16KB/block -> still
// 8 blocks / 32 waves per CU.

#define NBLOCKS  4096
#define NTHREADS 256
#define WAVES    (NTHREADS / 64)               // 4
#define NACC     5
#define M_ELEMS  16777216                      // 4096*4096
#define EPW      (M_ELEMS / (NBLOCKS * WAVES)) // 1024 elems per wave
#define ITERS    (EPW / 64)                    // 16 (even)
#define BUFB     2048                          // bytes per wave buffer
#define EPS      1e-5
#define OMEGA    1.0

typedef float f4 __attribute__((ext_vector_type(4)));
typedef float f2 __attribute__((ext_vector_type(2)));

__device__ __forceinline__ void gload16(const void* g, void* l) {
    __builtin_amdgcn_global_load_lds(
        (const __attribute__((address_space(1))) void*)g,
        (__attribute__((address_space(3))) void*)l, 16, 0, 0);
}

// Issue the 2 DMA calls for one 64-element iter into wave-private buffer.
// LDS layout: [cov 64*16B = 1024][pred 64*8B = 512][tgt 64*8B = 512].
// pred/tgt staged as 16B PAIRS: lanes 0-31 carry pred pairs -> bytes
// 1024..1535, lanes 32-63 carry tgt pairs -> bytes 1536..2047; element e's
// pred f2 lands at 1024+(e-ebase)*8, tgt at 1536+(e-ebase)*8 (linear).
__device__ __forceinline__ void stage(
    char* buf, const f4* __restrict__ cov,
    const f4* __restrict__ pred4, const f4* __restrict__ tgt4,
    int ebase, int lane)
{
    gload16(&cov[ebase + lane], buf);
    const int pb = (ebase >> 1) + (lane & 31);          // pair index
    const f4* s = (lane < 32) ? &pred4[pb] : &tgt4[pb]; // per-lane source
    gload16(s, buf + 1024);
}

// one 2x2 eigen-element: cov f4 c = [a, b, b, d], residual (dx, dy)
__device__ __forceinline__ void star_elem(
    f4 c, float dx, float dy,
    float& s1, float& s2, float& s3, float& s4, float& s5)
{
    const float a = c.x, b = c.y, d = c.w;
    float mean  = 0.5f * (a + d);
    float hd    = 0.5f * (a - d);
    float delta = sqrtf(hd * hd + b * b);
    float lam1  = mean + delta;
    float lam2  = mean - delta;           // >= 0.1 (PSD + 0.1*I)

    bool diag = fabsf(b) < 1e-12f;
    bool a_ge = (a >= d);
    float vx = diag ? (a_ge ? 1.0f : 0.0f) : b;
    float vy = diag ? (a_ge ? 0.0f : 1.0f) : (lam1 - a);
    float inv_n = rsqrtf(vx * vx + vy * vy);
    vx *= inv_n;
    vy *= inv_n;

    float r1 = vx * dx + vy * dy;
    float r2 = vx * dy - vy * dx;

    s1 += r1 * r1;
    s2 += r2 * r2;
    s3 += rsqrtf(lam1);
    s4 += rsqrtf(lam2);
    s5 += a + d;                          // trace = lam1 + lam2
}

__device__ __forceinline__ void consume(
    const char* buf, int lane,
    float& s1, float& s2, float& s3, float& s4, float& s5)
{
    f4 c = ((const f4*)(buf))[lane];
    f2 p = ((const f2*)(buf + 1024))[lane];
    f2 t = ((const f2*)(buf + 1536))[lane];
    star_elem(c, p.x - t.x, p.y - t.y, s1, s2, s3, s4, s5);
}

__device__ __forceinline__ float wave_reduce_f(float v) {
    #pragma unroll
    for (int off = 32; off > 0; off >>= 1) v += __shfl_down(v, off, 64);
    return v;
}

__global__ __launch_bounds__(NTHREADS) void star_partial(
    const f2* __restrict__ pred,   // M f2
    const f4* __restrict__ cov,    // M f4
    const f2* __restrict__ tgt,    // M f2
    float* __restrict__ partials)  // NBLOCKS * NACC
{
    __shared__ __align__(16) char lds[WAVES][2][BUFB];

    float s1 = 0.f, s2 = 0.f, s3 = 0.f, s4 = 0.f, s5 = 0.f;
    const int lane = threadIdx.x & 63;
    const int wid  = threadIdx.x >> 6;
    const int wbase = (blockIdx.x * WAVES + wid) * EPW;

    const f4* pred4 = (const f4*)pred;    // M/2 pairs
    const f4* tgt4  = (const f4*)tgt;

    char* buf0 = &lds[wid][0][0];
    char* buf1 = &lds[wid][1][0];

    stage(buf0, cov, pred4, tgt4, wbase, lane);          // iter 0: 2 calls out

    #pragma unroll
    for (int it = 0; it < ITERS; it += 2) {
        stage(buf1, cov, pred4, tgt4, wbase + (it + 1) * 64, lane);
        // buf0's 2 calls are the OLDEST; keep buf1's 2 in flight.
        asm volatile("s_waitcnt vmcnt(2)" ::: "memory");
        consume(buf0, lane, s1, s2, s3, s4, s5);
        if (it + 2 < ITERS) {
            stage(buf0, cov, pred4, tgt4, wbase + (it + 2) * 64, lane);
            asm volatile("s_waitcnt vmcnt(2)" ::: "memory");
        } else {
            asm volatile("s_waitcnt vmcnt(0)" ::: "memory");
        }
        consume(buf1, lane, s1, s2, s3, s4, s5);
    }

    float v[NACC] = {s1, s2, s3, s4, s5};
    #pragma unroll
    for (int k = 0; k < NACC; ++k) v[k] = wave_reduce_f(v[k]);

    __shared__ float red[WAVES][NACC];
    if (lane == 0) {
        #pragma unroll
        for (int k = 0; k < NACC; ++k) red[wid][k] = v[k];
    }
    __syncthreads();
    if (threadIdx.x == 0) {
        #pragma unroll
        for (int k = 0; k < NACC; ++k) {
            float acc = 0.f;
            #pragma unroll
            for (int w = 0; w < WAVES; ++w) acc += red[w][k];
            partials[blockIdx.x * NACC + k] = acc;
        }
    }
}

__global__ __launch_bounds__(NTHREADS) void star_final(
    const float* __restrict__ partials, float* __restrict__ out, int nblocks)
{
    double acc[NACC] = {0, 0, 0, 0, 0};
    for (int i = threadIdx.x; i < nblocks; i += NTHREADS) {
        #pragma unroll
        for (int k = 0; k < NACC; ++k) acc[k] += (double)partials[i * NACC + k];
    }

    #pragma unroll
    for (int k = 0; k < NACC; ++k) {
        #pragma unroll
        for (int off = 32; off > 0; off >>= 1)
            acc[k] += __shfl_down(acc[k], off, 64);
    }

    __shared__ double red[NTHREADS / 64][NACC];
    const int lane = threadIdx.x & 63;
    const int wid  = threadIdx.x >> 6;
    if (lane == 0) {
        #pragma unroll
        for (int k = 0; k < NACC; ++k) red[wid][k] = acc[k];
    }
    __syncthreads();

    if (threadIdx.x == 0) {
        double S[NACC];
        #pragma unroll
        for (int k = 0; k < NACC; ++k) {
            double t = 0.0;
            #pragma unroll
            for (int w = 0; w < NTHREADS / 64; ++w) t += red[w][k];
            S[k] = t;
        }
        const double M  = (double)M_ELEMS;
        const double S3 = S[2] + M * EPS;   // sum of (1/sqrt(lam1) + eps)
        const double S4 = S[3] + M * EPS;
        double loss = (S[0] * S3 + S[1] * S4 + 0.5 * OMEGA * S[4]) / M;
        out[0] = (float)loss;
    }
}

extern "C" void kernel_launch(void* const* d_in, const int* in_sizes, int n_in,
                              void* d_out, int out_size, void* d_ws, size_t ws_size,
                              hipStream_t stream) {
    const f2* pred = (const f2*)d_in[0];   // (B,N,2)   = M f2
    const f4* cov  = (const f4*)d_in[1];   // (B,N,2,2) = M f4
    const f2* tgt  = (const f2*)d_in[2];   // (B,N,2)   = M f2
    float* out      = (float*)d_out;
    float* partials = (float*)d_ws;        // NBLOCKS*NACC floats (80 KB)

    star_partial<<<NBLOCKS, NTHREADS, 0, stream>>>(pred, cov, tgt, partials);
    star_final<<<1, NTHREADS, 0, stream>>>(partials, out, NBLOCKS);
}